// Round 1
// baseline (602.682 us; speedup 1.0000x reference)
//
#include <hip/hip_runtime.h>
#include <stdint.h>

#define HB 16
#define HC 80
#define HH 256
#define HWD 256
#define PLANE (HH * HWD)        // 65536
#define NPLANES (HB * HC)       // 1280
#define K_TOP 100
#define CAP 2048                // per-plane candidate buffer
#define OUTCAP 256
#define NEG_INF (-3.402823466e38f)

__device__ __forceinline__ int blockReduceSum(int v, int* sred) {
    // 256 threads = 4 waves of 64
    for (int off = 32; off > 0; off >>= 1) v += __shfl_down(v, off);
    int t = threadIdx.x;
    __syncthreads();                    // protect sred reuse across calls
    if ((t & 63) == 0) sred[t >> 6] = v;
    __syncthreads();
    return sred[0] + sred[1] + sred[2] + sred[3];
}

__device__ __forceinline__ bool better(float a, int ai, float b, int bi) {
    return (a > b) || (a == b && ai < bi);
}

// descending sort of 256 (val,idx) pairs, ties -> smaller idx first
__device__ void bitonic256(float* sv, int* si) {
    int t = threadIdx.x;
    for (unsigned k = 2; k <= 256; k <<= 1) {
        for (unsigned j = k >> 1; j > 0; j >>= 1) {
            __syncthreads();
            unsigned i = (unsigned)t, x = i ^ j;
            if (x > i) {
                float a = sv[i], bv = sv[x];
                int ai = si[i], bi = si[x];
                bool sw = ((i & k) == 0) ? better(bv, bi, a, ai) : better(a, ai, bv, bi);
                if (sw) { sv[i] = bv; si[i] = bi; sv[x] = a; si[x] = ai; }
            }
        }
    }
    __syncthreads();
}

// One block per (b,c) plane: 3x3 NMS + exact per-plane top-100 -> ws
__global__ __launch_bounds__(256) void k_plane_topk(const float* __restrict__ heat,
                                                    float* __restrict__ wsv,
                                                    int* __restrict__ wsi) {
    int plane = blockIdx.x;             // b*HC + c
    int c = plane % HC;
    const float* pl = heat + (size_t)plane * PLANE;
    int t = threadIdx.x;

    __shared__ float rb[3][HWD + 2];
    __shared__ float bufv[CAP];
    __shared__ int   bufi[CAP];
    __shared__ float outv[OUTCAP];
    __shared__ int   outi[OUTCAP];
    __shared__ int   cnt, cnt2;
    __shared__ int   sred[4];

    if (t < 3) { rb[t][0] = NEG_INF; rb[t][HWD + 1] = NEG_INF; }

    float thr = 0.98f;
    int n = 0;
    for (int attempt = 0; attempt < 3; ++attempt) {
        if (t == 0) cnt = 0;
        __syncthreads();
        // stream plane: separable 3x3 max (row h-max in LDS, vertical in regs)
        rb[0][t + 1] = pl[t];
        __syncthreads();
        float h0 = fmaxf(fmaxf(rb[0][t], rb[0][t + 1]), rb[0][t + 2]);
        float v0 = rb[0][t + 1];
        float hm1 = NEG_INF;
        for (int r = 0; r < HH; ++r) {
            int rn = r + 1;
            float h1 = NEG_INF, v1 = 0.0f;
            if (rn < HH) {
                __syncthreads();
                rb[rn % 3][t + 1] = pl[rn * HWD + t];
                __syncthreads();
                const float* rbn = rb[rn % 3];
                h1 = fmaxf(fmaxf(rbn[t], rbn[t + 1]), rbn[t + 2]);
                v1 = rbn[t + 1];
            }
            float pooled = fmaxf(fmaxf(hm1, h0), h1);
            if (v0 >= pooled && v0 > thr) {          // NMS keep && above collect thr
                int p = atomicAdd(&cnt, 1);
                if (p < CAP) { bufv[p] = v0; bufi[p] = (c << 16) | (r << 8) | t; }
            }
            hm1 = h0; h0 = h1; v0 = v1;
        }
        __syncthreads();
        n = cnt;
        __syncthreads();                 // everyone read cnt before any reset
        if (n >= K_TOP && n <= CAP) break;
        if (n > CAP) thr = 1.0f - (1.0f - thr) * 0.25f;   // too many: raise
        else thr = (attempt == 0) ? 0.5f : 0.01f;         // too few: lower
    }
    int nn = min(n, CAP);

    // load candidates to regs for counting
    float regv[CAP / 256];
#pragma unroll
    for (int k = 0; k < CAP / 256; ++k) {
        int s = t + (k << 8);
        regv[k] = (s < nn) ? bufv[s] : NEG_INF;
    }

    // bit-space binary search for the 100th-largest value
    float T100;
    if (nn >= K_TOP) {
        unsigned lo = 0u, hi = 0x7f800000u;     // cnt(0.0)>=100 (all vals>0.01), cnt(inf)=0
        while (hi - lo > 1u) {
            unsigned mid = (lo + hi) >> 1u;
            float mv = __uint_as_float(mid);
            int cl = 0;
#pragma unroll
            for (int k = 0; k < CAP / 256; ++k) cl += (regv[k] >= mv) ? 1 : 0;
            int tot = blockReduceSum(cl, sred);
            if (tot >= K_TOP) lo = mid; else hi = mid;
        }
        T100 = __uint_as_float(lo);
    } else {
        T100 = NEG_INF;
    }

    // collect all >= T100 (typically exactly 100)
    outv[t] = NEG_INF; outi[t] = 0x7fffffff;
    if (t == 0) cnt2 = 0;
    __syncthreads();
#pragma unroll
    for (int k = 0; k < CAP / 256; ++k) {
        int s = t + (k << 8);
        if (s < nn && bufv[s] >= T100) {
            int p = atomicAdd(&cnt2, 1);
            if (p < OUTCAP) { outv[p] = bufv[s]; outi[p] = bufi[s]; }
        }
    }
    __syncthreads();
    int c2 = cnt2;
    if (c2 > K_TOP) bitonic256(outv, outi);   // ties straddle cut: order by (val desc, idx asc)
    __syncthreads();
    if (t < K_TOP) {
        wsv[plane * K_TOP + t] = outv[t];
        wsi[plane * K_TOP + t] = outi[t];
    }
}

// One block per batch: exact top-100 of 80*100 candidates + epilogue
__global__ __launch_bounds__(256) void k_batch_out(const float* __restrict__ wsv,
                                                   const int* __restrict__ wsi,
                                                   const float* __restrict__ offset,
                                                   const float* __restrict__ wh,
                                                   float* __restrict__ out) {
    int b = blockIdx.x;
    int t = threadIdx.x;
    const int NCAND = HC * K_TOP;       // 8000
    const float* v_in = wsv + b * NCAND;
    const int*   i_in = wsi + b * NCAND;

    __shared__ float outv[OUTCAP];
    __shared__ int   outi[OUTCAP];
    __shared__ int   cnt2;
    __shared__ int   sred[4];

    float regv[32];
#pragma unroll
    for (int k = 0; k < 32; ++k) {
        int s = t + (k << 8);
        regv[k] = (s < NCAND) ? v_in[s] : NEG_INF;
    }
    int cl0 = 0;
#pragma unroll
    for (int k = 0; k < 32; ++k) cl0 += (regv[k] > NEG_INF) ? 1 : 0;
    int nreal = blockReduceSum(cl0, sred);

    float T100;
    if (nreal >= K_TOP) {
        unsigned lo = 0u, hi = 0x7f800000u;
        while (hi - lo > 1u) {
            unsigned mid = (lo + hi) >> 1u;
            float mv = __uint_as_float(mid);
            int cl = 0;
#pragma unroll
            for (int k = 0; k < 32; ++k) cl += (regv[k] >= mv) ? 1 : 0;
            int tot = blockReduceSum(cl, sred);
            if (tot >= K_TOP) lo = mid; else hi = mid;
        }
        T100 = __uint_as_float(lo);
    } else {
        T100 = NEG_INF;
    }

    outv[t] = NEG_INF; outi[t] = 0x7fffffff;
    if (t == 0) cnt2 = 0;
    __syncthreads();
#pragma unroll
    for (int k = 0; k < 32; ++k) {
        int s = t + (k << 8);
        if (s < NCAND && regv[k] >= T100 && regv[k] > NEG_INF) {
            int p = atomicAdd(&cnt2, 1);
            if (p < OUTCAP) { outv[p] = regv[k]; outi[p] = i_in[s]; }
        }
    }
    __syncthreads();
    bitonic256(outv, outi);             // need descending output order

    if (t < K_TOP) {
        float val = outv[t];
        int idx = outi[t];
        bool valid = val > 0.01f;       // EXCEPT_THRESH, strict
        int cch = idx >> 16;
        int spatial = idx & 0xFFFF;
        int y = spatial >> 8, x = spatial & 0xFF;
        const float* offb = offset + (size_t)b * 2 * PLANE;
        const float* whb  = wh     + (size_t)b * 2 * PLANE;
        float o0 = offb[spatial], o1 = offb[PLANE + spatial];
        float w0 = whb[spatial],  w1 = whb[PLANE + spatial];
        float cx = (float)x + o0, cy = (float)y + o1;
        float hw = w0 * 0.5f, hh = w1 * 0.5f;
        int g = b * K_TOP + t;
        out[g]                = valid ? (float)cch : -1.0f;
        out[HB * K_TOP + g]   = valid ? val        : -1.0f;
        float b0 = valid ? (cx - hw) : -1.0f;     // mask applied BEFORE *SCALE (masked -> -4)
        float b1 = valid ? (cy - hh) : -1.0f;
        float b2 = valid ? (cx + hw) : -1.0f;
        float b3 = valid ? (cy + hh) : -1.0f;
        float* bb = out + 2 * HB * K_TOP + 4 * g;
        bb[0] = b0 * 4.0f; bb[1] = b1 * 4.0f; bb[2] = b2 * 4.0f; bb[3] = b3 * 4.0f;
    }
}

extern "C" void kernel_launch(void* const* d_in, const int* in_sizes, int n_in,
                              void* d_out, int out_size, void* d_ws, size_t ws_size,
                              hipStream_t stream) {
    (void)in_sizes; (void)n_in; (void)out_size; (void)ws_size;
    const float* heat   = (const float*)d_in[0];
    const float* offset = (const float*)d_in[1];
    const float* wh     = (const float*)d_in[2];
    float* out = (float*)d_out;
    float* wsv = (float*)d_ws;                                   // 128000 floats
    int*   wsi = (int*)((char*)d_ws + (size_t)NPLANES * K_TOP * sizeof(float));

    k_plane_topk<<<NPLANES, 256, 0, stream>>>(heat, wsv, wsi);
    k_batch_out<<<HB, 256, 0, stream>>>(wsv, wsi, offset, wh, out);
}

// Round 2
// 509.265 us; speedup vs baseline: 1.1834x; 1.1834x over previous
//
#include <hip/hip_runtime.h>
#include <stdint.h>

#define HB 16
#define HC 80
#define HH 256
#define HWD 256
#define PLANE (HH * HWD)        // 65536
#define NPLANES (HB * HC)       // 1280
#define K_TOP 100
#define CAP 2048                // per-plane candidate buffer
#define OUTCAP 256
#define NEG_INF (-3.402823466e38f)

__device__ __forceinline__ int blockReduceSum(int v, int* sred) {
    // 256 threads = 4 waves of 64
    for (int off = 32; off > 0; off >>= 1) v += __shfl_down(v, off);
    int t = threadIdx.x;
    __syncthreads();                    // protect sred reuse across calls
    if ((t & 63) == 0) sred[t >> 6] = v;
    __syncthreads();
    return sred[0] + sred[1] + sred[2] + sred[3];
}

__device__ __forceinline__ bool better(float a, int ai, float b, int bi) {
    return (a > b) || (a == b && ai < bi);
}

// descending sort of 256 (val,idx) pairs, ties -> smaller idx first
__device__ void bitonic256(float* sv, int* si) {
    int t = threadIdx.x;
    for (unsigned k = 2; k <= 256; k <<= 1) {
        for (unsigned j = k >> 1; j > 0; j >>= 1) {
            __syncthreads();
            unsigned i = (unsigned)t, x = i ^ j;
            if (x > i) {
                float a = sv[i], bv = sv[x];
                int ai = si[i], bi = si[x];
                bool sw = ((i & k) == 0) ? better(bv, bi, a, ai) : better(a, ai, bv, bi);
                if (sw) { sv[i] = bv; si[i] = bi; sv[x] = a; si[x] = ai; }
            }
        }
    }
    __syncthreads();
}

// branchless row load: clamp row, select NEG_INF if out of plane.
// keeps loads unconditional so 4 can issue back-to-back (vmcnt depth 4)
__device__ __forceinline__ float4 loadrow(const float* __restrict__ pl, int r, int lane) {
    int rc = min(max(r, 0), HH - 1);
    float4 v = ((const float4*)(pl + rc * HWD))[lane];
    if (r != rc) { v.x = NEG_INF; v.y = NEG_INF; v.z = NEG_INF; v.w = NEG_INF; }
    return v;
}

// horizontal 3-max for 4 consecutive cols owned by this lane.
// neighbors via wave shuffle; lane 0 / 63 are plane column edges (-inf pad).
__device__ __forceinline__ float4 hmax4(float4 v, int lane) {
    float vl = __shfl_up(v.w, 1);
    float vr = __shfl_down(v.x, 1);
    if (lane == 0) vl = NEG_INF;
    if (lane == 63) vr = NEG_INF;
    float4 h;
    h.x = fmaxf(fmaxf(vl, v.x), v.y);
    h.y = fmaxf(fmaxf(v.x, v.y), v.z);
    h.z = fmaxf(fmaxf(v.y, v.z), v.w);
    h.w = fmaxf(fmaxf(v.z, v.w), vr);
    return h;
}

// One block per (b,c) plane. Wave w streams rows [64w, 64w+63] with rolling
// vertical window in registers -- NO barriers in the streaming loop.
__global__ __launch_bounds__(256) void k_plane_topk(const float* __restrict__ heat,
                                                    float* __restrict__ wsv,
                                                    int* __restrict__ wsi) {
    int plane = blockIdx.x;             // b*HC + c
    int c = plane % HC;
    const float* pl = heat + (size_t)plane * PLANE;
    int t = threadIdx.x;
    int lane = t & 63;
    int rs = (t >> 6) << 6;             // wave's first output row

    __shared__ float bufv[CAP];
    __shared__ int   bufi[CAP];
    __shared__ float outv[OUTCAP];
    __shared__ int   outi[OUTCAP];
    __shared__ int   cnt, cnt2;
    __shared__ int   sred[4];

    float thr = 0.98f;
    int n = 0;
    for (int attempt = 0; attempt < 3; ++attempt) {
        if (t == 0) cnt = 0;
        __syncthreads();

        float4 rm1 = loadrow(pl, rs - 1, lane);
        float4 r0  = loadrow(pl, rs, lane);
        float4 hA = hmax4(rm1, lane);
        float4 hB = hmax4(r0, lane);
        float4 vB = r0;

        for (int i = 0; i < 64; i += 4) {
            // 4 independent loads in flight
            float4 n0 = loadrow(pl, rs + i + 1, lane);
            float4 n1 = loadrow(pl, rs + i + 2, lane);
            float4 n2 = loadrow(pl, rs + i + 3, lane);
            float4 n3 = loadrow(pl, rs + i + 4, lane);
#pragma unroll
            for (int u = 0; u < 4; ++u) {
                float4 nr = (u == 0) ? n0 : (u == 1) ? n1 : (u == 2) ? n2 : n3;
                int row = rs + i + u;
                float4 hC = hmax4(nr, lane);
                float p0 = fmaxf(fmaxf(hA.x, hB.x), hC.x);
                float p1 = fmaxf(fmaxf(hA.y, hB.y), hC.y);
                float p2 = fmaxf(fmaxf(hA.z, hB.z), hC.z);
                float p3 = fmaxf(fmaxf(hA.w, hB.w), hC.w);
                int colb = lane << 2;
                if (vB.x >= p0 && vB.x > thr) {
                    int p = atomicAdd(&cnt, 1);
                    if (p < CAP) { bufv[p] = vB.x; bufi[p] = (c << 16) | (row << 8) | colb; }
                }
                if (vB.y >= p1 && vB.y > thr) {
                    int p = atomicAdd(&cnt, 1);
                    if (p < CAP) { bufv[p] = vB.y; bufi[p] = (c << 16) | (row << 8) | (colb + 1); }
                }
                if (vB.z >= p2 && vB.z > thr) {
                    int p = atomicAdd(&cnt, 1);
                    if (p < CAP) { bufv[p] = vB.z; bufi[p] = (c << 16) | (row << 8) | (colb + 2); }
                }
                if (vB.w >= p3 && vB.w > thr) {
                    int p = atomicAdd(&cnt, 1);
                    if (p < CAP) { bufv[p] = vB.w; bufi[p] = (c << 16) | (row << 8) | (colb + 3); }
                }
                hA = hB; hB = hC; vB = nr;
            }
        }
        __syncthreads();
        n = cnt;
        __syncthreads();                 // everyone read cnt before any reset
        if (n >= K_TOP && n <= CAP) break;
        if (n > CAP) thr = 1.0f - (1.0f - thr) * 0.25f;   // too many: raise
        else thr = (attempt == 0) ? 0.5f : 0.01f;         // too few: lower
    }
    int nn = min(n, CAP);

    // load candidates to regs for counting
    float regv[CAP / 256];
#pragma unroll
    for (int k = 0; k < CAP / 256; ++k) {
        int s = t + (k << 8);
        regv[k] = (s < nn) ? bufv[s] : NEG_INF;
    }

    // bit-space binary search for the 100th-largest value
    float T100;
    if (nn >= K_TOP) {
        unsigned lo = 0u, hi = 0x7f800000u;
        while (hi - lo > 1u) {
            unsigned mid = (lo + hi) >> 1u;
            float mv = __uint_as_float(mid);
            int cl = 0;
#pragma unroll
            for (int k = 0; k < CAP / 256; ++k) cl += (regv[k] >= mv) ? 1 : 0;
            int tot = blockReduceSum(cl, sred);
            if (tot >= K_TOP) lo = mid; else hi = mid;
        }
        T100 = __uint_as_float(lo);
    } else {
        T100 = NEG_INF;
    }

    // collect all >= T100 (typically exactly 100)
    outv[t] = NEG_INF; outi[t] = 0x7fffffff;
    if (t == 0) cnt2 = 0;
    __syncthreads();
#pragma unroll
    for (int k = 0; k < CAP / 256; ++k) {
        int s = t + (k << 8);
        if (s < nn && bufv[s] >= T100) {
            int p = atomicAdd(&cnt2, 1);
            if (p < OUTCAP) { outv[p] = bufv[s]; outi[p] = bufi[s]; }
        }
    }
    __syncthreads();
    int c2 = cnt2;
    if (c2 > K_TOP) bitonic256(outv, outi);   // ties straddle cut: order by (val desc, idx asc)
    __syncthreads();
    if (t < K_TOP) {
        wsv[plane * K_TOP + t] = outv[t];
        wsi[plane * K_TOP + t] = outi[t];
    }
}

// One block per batch: exact top-100 of 80*100 candidates + epilogue
__global__ __launch_bounds__(256) void k_batch_out(const float* __restrict__ wsv,
                                                   const int* __restrict__ wsi,
                                                   const float* __restrict__ offset,
                                                   const float* __restrict__ wh,
                                                   float* __restrict__ out) {
    int b = blockIdx.x;
    int t = threadIdx.x;
    const int NCAND = HC * K_TOP;       // 8000
    const float* v_in = wsv + b * NCAND;
    const int*   i_in = wsi + b * NCAND;

    __shared__ float outv[OUTCAP];
    __shared__ int   outi[OUTCAP];
    __shared__ int   cnt2;
    __shared__ int   sred[4];

    float regv[32];
#pragma unroll
    for (int k = 0; k < 32; ++k) {
        int s = t + (k << 8);
        regv[k] = (s < NCAND) ? v_in[s] : NEG_INF;
    }
    int cl0 = 0;
#pragma unroll
    for (int k = 0; k < 32; ++k) cl0 += (regv[k] > NEG_INF) ? 1 : 0;
    int nreal = blockReduceSum(cl0, sred);

    float T100;
    if (nreal >= K_TOP) {
        unsigned lo = 0u, hi = 0x7f800000u;
        while (hi - lo > 1u) {
            unsigned mid = (lo + hi) >> 1u;
            float mv = __uint_as_float(mid);
            int cl = 0;
#pragma unroll
            for (int k = 0; k < 32; ++k) cl += (regv[k] >= mv) ? 1 : 0;
            int tot = blockReduceSum(cl, sred);
            if (tot >= K_TOP) lo = mid; else hi = mid;
        }
        T100 = __uint_as_float(lo);
    } else {
        T100 = NEG_INF;
    }

    outv[t] = NEG_INF; outi[t] = 0x7fffffff;
    if (t == 0) cnt2 = 0;
    __syncthreads();
#pragma unroll
    for (int k = 0; k < 32; ++k) {
        int s = t + (k << 8);
        if (s < NCAND && regv[k] >= T100 && regv[k] > NEG_INF) {
            int p = atomicAdd(&cnt2, 1);
            if (p < OUTCAP) { outv[p] = regv[k]; outi[p] = i_in[s]; }
        }
    }
    __syncthreads();
    bitonic256(outv, outi);             // need descending output order

    if (t < K_TOP) {
        float val = outv[t];
        int idx = outi[t];
        bool valid = val > 0.01f;       // EXCEPT_THRESH, strict
        int cch = idx >> 16;
        int spatial = idx & 0xFFFF;
        int y = spatial >> 8, x = spatial & 0xFF;
        const float* offb = offset + (size_t)b * 2 * PLANE;
        const float* whb  = wh     + (size_t)b * 2 * PLANE;
        float o0 = offb[spatial], o1 = offb[PLANE + spatial];
        float w0 = whb[spatial],  w1 = whb[PLANE + spatial];
        float cx = (float)x + o0, cy = (float)y + o1;
        float hw = w0 * 0.5f, hh = w1 * 0.5f;
        int g = b * K_TOP + t;
        out[g]                = valid ? (float)cch : -1.0f;
        out[HB * K_TOP + g]   = valid ? val        : -1.0f;
        float b0 = valid ? (cx - hw) : -1.0f;     // mask applied BEFORE *SCALE (masked -> -4)
        float b1 = valid ? (cy - hh) : -1.0f;
        float b2 = valid ? (cx + hw) : -1.0f;
        float b3 = valid ? (cy + hh) : -1.0f;
        float* bb = out + 2 * HB * K_TOP + 4 * g;
        bb[0] = b0 * 4.0f; bb[1] = b1 * 4.0f; bb[2] = b2 * 4.0f; bb[3] = b3 * 4.0f;
    }
}

extern "C" void kernel_launch(void* const* d_in, const int* in_sizes, int n_in,
                              void* d_out, int out_size, void* d_ws, size_t ws_size,
                              hipStream_t stream) {
    (void)in_sizes; (void)n_in; (void)out_size; (void)ws_size;
    const float* heat   = (const float*)d_in[0];
    const float* offset = (const float*)d_in[1];
    const float* wh     = (const float*)d_in[2];
    float* out = (float*)d_out;
    float* wsv = (float*)d_ws;                                   // 128000 floats
    int*   wsi = (int*)((char*)d_ws + (size_t)NPLANES * K_TOP * sizeof(float));

    k_plane_topk<<<NPLANES, 256, 0, stream>>>(heat, wsv, wsi);
    k_batch_out<<<HB, 256, 0, stream>>>(wsv, wsi, offset, wh, out);
}